// Round 6
// baseline (178.881 us; speedup 1.0000x reference)
//
#include <hip/hip_runtime.h>
#include <hip/hip_bf16.h>

#define B_ 64
#define C_ 512
#define HW_ 1024
#define R_ 32
#define NCHUNK 4
#define CPB 128   // channels per chunk
#define Q_ 4      // pixel quarters
#define PPB 256   // pixels per block

// ---------------------------------------------------------------------------
// A: one pass over x. Block = (b, c-chunk, pixel-quarter); 256 threads,
// 1 pixel/thread. Grid = 1024 blocks -> 4 blocks/CU, 16 waves/CU.
// Weights transposed-gathered into LDS once per block (uniform broadcast
// reads in the loop). Pooled via 3-shuffle fold + [128][33] LDS partials.
// ---------------------------------------------------------------------------
__global__ __launch_bounds__(256, 4) void k_proj(
    const float* __restrict__ x, const float* __restrict__ w_eig,
    const float* __restrict__ w_sp,
    __hip_bfloat16* __restrict__ featp, __hip_bfloat16* __restrict__ sppb,
    float* __restrict__ pooledp)
{
    const int t   = threadIdx.x;         // 0..255
    const int blk = blockIdx.x;          // ((b*4)+ch)*4 + q
    const int q   = blk & 3;
    const int ch  = (blk >> 2) & 3;
    const int b   = blk >> 4;
    const int c0  = ch * CPB;
    const int n   = q * PPB + t;         // this thread's pixel

    __shared__ float wlds[CPB * R_];     // 16 KB, [channel][r] transposed
    __shared__ float wsp_l[CPB];         // 512 B
    __shared__ float plds[CPB][33];      // 16.9 KB pooled partials (padded)
    __shared__ float red2[CPB][2];       // 1 KB

    // transpose-gather w_eig chunk: wlds[c*32+r] = w_eig[r*512 + c0+c]
    for (int i = t; i < CPB * R_; i += 256) {
        int c = i >> 5, r = i & 31;
        wlds[i] = w_eig[(size_t)r * C_ + c0 + c];
    }
    if (t < CPB) wsp_l[t] = w_sp[c0 + t];
    __syncthreads();

    float acc[R_];
#pragma unroll
    for (int r = 0; r < R_; ++r) acc[r] = 0.f;
    float sp = 0.f;

    const float* xb = x + ((size_t)(b * C_ + c0)) * HW_ + n;

    float xv = xb[0];
    for (int j = 0; j < CPB; ++j) {
        // prefetch next channel's pixel (wraps harmlessly on last iter)
        float xn = xb[(size_t)((j + 1) & (CPB - 1)) * HW_];

        const float4* wr = (const float4*)(wlds + j * R_);  // uniform addr
#pragma unroll
        for (int k = 0; k < 8; ++k) {
            float4 w = wr[k];
            acc[4 * k + 0] = fmaf(w.x, xv, acc[4 * k + 0]);
            acc[4 * k + 1] = fmaf(w.y, xv, acc[4 * k + 1]);
            acc[4 * k + 2] = fmaf(w.z, xv, acc[4 * k + 2]);
            acc[4 * k + 3] = fmaf(w.w, xv, acc[4 * k + 3]);
        }

        sp = fmaf(wsp_l[j], xv, sp);

        // pooled partial: fold 8 lanes, 32 partials per channel
        float s = xv;
        s += __shfl_xor(s, 1, 64);
        s += __shfl_xor(s, 2, 64);
        s += __shfl_xor(s, 4, 64);
        if ((t & 7) == 0) plds[j][t >> 3] = s;

        xv = xn;
    }
    __syncthreads();

    // pooled final reduce: thread t -> channel t>>1, half t&1 (16 values)
    {
        const int j = t >> 1, h = t & 1;
        float s = 0.f;
#pragma unroll
        for (int i = 0; i < 16; ++i) s += plds[j][h * 16 + i];
        red2[j][h] = s;
    }
    __syncthreads();
    if (t < CPB)
        pooledp[(((size_t)q * B_ + b) * C_) + c0 + t] = red2[t][0] + red2[t][1];

    sppb[((size_t)(ch * B_ + b)) * HW_ + n] = __float2bfloat16(sp);

    // featp bf16, layout [(ch*B+b)*HW + n][r] -> 64B per thread
    __hip_bfloat16* fb = featp + ((size_t)((ch * B_ + b) * HW_ + n)) * R_;
    union { __hip_bfloat16 h[R_]; uint4 qv[4]; } u;
#pragma unroll
    for (int r = 0; r < R_; ++r) u.h[r] = __float2bfloat16(acc[r]);
#pragma unroll
    for (int k = 0; k < 4; ++k) ((uint4*)fb)[k] = u.qv[k];
}

// ---------------------------------------------------------------------------
// B: per-batch block (64 blocks, 1024 threads = one per pixel).
// pooled = sum of 4 q-partials (LDS-staged); mean[r] & fc1; channel attn;
// power iteration with column F_c[:,n] in registers; att -> min/max ->
// sigmoid; att_all = eigen_att * spatial_att.
// ---------------------------------------------------------------------------
__global__ __launch_bounds__(1024) void k_eigen(
    const __hip_bfloat16* __restrict__ featp,
    const __hip_bfloat16* __restrict__ sppb,
    const float* __restrict__ pooledp,
    const float* __restrict__ w_eig, const float* __restrict__ w_fc1,
    const float* __restrict__ b_fc1, const float* __restrict__ w_fc2,
    const float* __restrict__ b_fc2, const float* __restrict__ b_sp,
    const float* __restrict__ v0,
    float* __restrict__ ca_out, float* __restrict__ att_out)
{
    const int b    = blockIdx.x;
    const int t    = threadIdx.x;
    const int lane = t & 63;
    const int wave = t >> 6;

    __shared__ float pooledm[C_];
    __shared__ float meanv[R_], t1[R_], vv[R_];
    __shared__ float part[R_][17];
    __shared__ float redmn[16], redmx[16], scal[2];

    // ---- pooled mean: combine the 4 pixel-quarter partials
    if (t < C_) {
        float s = 0.f;
#pragma unroll
        for (int qq = 0; qq < Q_; ++qq)
            s += pooledp[((size_t)qq * B_ + b) * C_ + t];
        pooledm[t] = s * (1.f / 1024.f);
    }
    __syncthreads();

    // ---- mean[r] = (w_eig @ pooled_mean)[r]; t1[r] = relu(fc1 @ pm + b)
    if (t < 512) {
        const int r = t >> 4, k = t & 15;
        float pm = 0.f, pf = 0.f;
        for (int c = k; c < C_; c += 16) {
            float p = pooledm[c];
            pm = fmaf(w_eig[r * C_ + c], p, pm);
            pf = fmaf(w_fc1[r * C_ + c], p, pf);
        }
#pragma unroll
        for (int m = 8; m > 0; m >>= 1) {
            pm += __shfl_xor(pm, m, 64);
            pf += __shfl_xor(pf, m, 64);
        }
        if (k == 0) { meanv[r] = pm; t1[r] = fmaxf(pf + b_fc1[r], 0.f); }
    }
    __syncthreads();

    // ---- channel attention ca[c] = sigmoid(w_fc2[c,:] @ t1 + b_fc2[c])
    if (t < C_) {
        float s = b_fc2[t];
        const float4* w4 = (const float4*)(w_fc2 + (size_t)t * R_);
#pragma unroll
        for (int k = 0; k < 8; ++k) {
            float4 w = w4[k];
            s = fmaf(w.x, t1[4 * k + 0], s);
            s = fmaf(w.y, t1[4 * k + 1], s);
            s = fmaf(w.z, t1[4 * k + 2], s);
            s = fmaf(w.w, t1[4 * k + 3], s);
        }
        ca_out[b * C_ + t] = 1.f / (1.f + expf(-s));
    }

    // ---- build centered column F_c[:, t] in registers (b_eig cancels)
    float col[R_];
#pragma unroll
    for (int r = 0; r < R_; ++r) col[r] = -meanv[r];
    for (int ch = 0; ch < NCHUNK; ++ch) {
        union { __hip_bfloat16 h[R_]; uint4 qv[4]; } u;
        const uint4* src =
            (const uint4*)(featp + ((size_t)((ch * B_ + b) * HW_ + t)) * R_);
#pragma unroll
        for (int k = 0; k < 4; ++k) u.qv[k] = src[k];
#pragma unroll
        for (int r = 0; r < R_; ++r) col[r] += __bfloat162float(u.h[r]);
    }

    // ---- v = v0 / ||v0||
    if (t < 64) {
        float vl = (t < R_) ? v0[b * R_ + t] : 0.f;
        float sq = vl * vl;
#pragma unroll
        for (int m = 32; m > 0; m >>= 1) sq += __shfl_xor(sq, m, 64);
        if (t < R_) vv[t] = vl / sqrtf(sq);
    }
    __syncthreads();

    // ---- 5 power iterations: v <- normalize(F (F^T v)/1023 + 1e-5 v)
    for (int it = 0; it < 5; ++it) {
        float uacc = 0.f;
#pragma unroll
        for (int r = 0; r < R_; ++r) uacc = fmaf(col[r], vv[r], uacc);
        uacc *= (1.f / 1023.f);

#pragma unroll
        for (int r = 0; r < R_; ++r) {
            float s = col[r] * uacc;
#pragma unroll
            for (int m = 32; m > 0; m >>= 1) s += __shfl_xor(s, m, 64);
            if (lane == 0) part[r][wave] = s;
        }
        __syncthreads();

        if (t < 64) {
            float w = 0.f;
            if (t < R_) {
                w = 1e-5f * vv[t];
#pragma unroll
                for (int wv = 0; wv < 16; ++wv) w += part[t][wv];
            }
            float sq = w * w;
#pragma unroll
            for (int m = 32; m > 0; m >>= 1) sq += __shfl_xor(sq, m, 64);
            if (t < R_) vv[t] = w / (sqrtf(sq) + 1e-10f);
        }
        __syncthreads();
    }

    // ---- att, min/max, eigen_att, spatial_att
    float a = 0.f;
#pragma unroll
    for (int r = 0; r < R_; ++r) a = fmaf(col[r], vv[r], a);

    float mn = a, mx = a;
#pragma unroll
    for (int m = 32; m > 0; m >>= 1) {
        mn = fminf(mn, __shfl_xor(mn, m, 64));
        mx = fmaxf(mx, __shfl_xor(mx, m, 64));
    }
    if (lane == 0) { redmn[wave] = mn; redmx[wave] = mx; }
    __syncthreads();
    if (t == 0) {
        float m1 = redmn[0], m2 = redmx[0];
        for (int w = 1; w < 16; ++w) {
            m1 = fminf(m1, redmn[w]);
            m2 = fmaxf(m2, redmx[w]);
        }
        scal[0] = m1; scal[1] = m2;
    }
    __syncthreads();

    const float amin  = scal[0];
    const float denom = (scal[1] - scal[0]) + 1e-10f;
    float eig = 1.f / (1.f + expf(-((a - amin) / denom)));

    float ssum = b_sp[0];
#pragma unroll
    for (int ch = 0; ch < NCHUNK; ++ch)
        ssum += __bfloat162float(sppb[((size_t)(ch * B_ + b)) * HW_ + t]);
    float spsig = 1.f / (1.f + expf(-ssum));

    att_out[b * HW_ + t] = eig * spsig;
}

// ---------------------------------------------------------------------------
// C: out = x * (1 + ca[b,c] * att_all[b,n]), float4 streaming.
// ---------------------------------------------------------------------------
__global__ __launch_bounds__(256) void k_final(
    const float* __restrict__ x, const float* __restrict__ ca,
    const float* __restrict__ att, float* __restrict__ out)
{
    const int t   = threadIdx.x;
    const int blk = blockIdx.x;          // b*C_ + c
    const int b   = blk >> 9;
    const float cav  = ca[blk];
    const size_t base = (size_t)blk * HW_;

    float4 xv = ((const float4*)(x + base))[t];
    float4 av = ((const float4*)(att + (size_t)b * HW_))[t];
    float4 o;
    o.x = fmaf(xv.x * cav, av.x, xv.x);
    o.y = fmaf(xv.y * cav, av.y, xv.y);
    o.z = fmaf(xv.z * cav, av.z, xv.z);
    o.w = fmaf(xv.w * cav, av.w, xv.w);
    ((float4*)(out + base))[t] = o;
}

// ---------------------------------------------------------------------------
extern "C" void kernel_launch(void* const* d_in, const int* in_sizes, int n_in,
                              void* d_out, int out_size, void* d_ws, size_t ws_size,
                              hipStream_t stream) {
    const float* x     = (const float*)d_in[0];
    const float* w_fc1 = (const float*)d_in[1];
    const float* b_fc1 = (const float*)d_in[2];
    const float* w_fc2 = (const float*)d_in[3];
    const float* b_fc2 = (const float*)d_in[4];
    const float* w_eig = (const float*)d_in[5];
    // d_in[6] = b_eig: cancels under mean-centering; unused.
    const float* w_sp  = (const float*)d_in[7];
    const float* b_sp  = (const float*)d_in[8];
    const float* v0    = (const float*)d_in[9];
    float* out = (float*)d_out;

    // workspace layout (bytes); total 18,219,008 (< proven 18,415,616)
    char* ws = (char*)d_ws;
    __hip_bfloat16* featp = (__hip_bfloat16*)ws;             // 16,777,216: 4*64*1024*32 bf16
    __hip_bfloat16* sppb  = (__hip_bfloat16*)(ws + 16777216);//    524,288: 4*64*1024 bf16
    float* pooledp = (float*)(ws + 17301504);                //    524,288: 4*64*512 f32 (q-partial sums)
    float* ca      = (float*)(ws + 17825792);                //    131,072: 64*512 f32
    float* att     = (float*)(ws + 17956864);                //    262,144: 64*1024 f32

    k_proj<<<B_ * NCHUNK * Q_, 256, 0, stream>>>(x, w_eig, w_sp,
                                                 featp, sppb, pooledp);
    k_eigen<<<B_, 1024, 0, stream>>>(featp, sppb, pooledp, w_eig, w_fc1, b_fc1,
                                     w_fc2, b_fc2, b_sp, v0, ca, att);
    k_final<<<B_ * C_, 256, 0, stream>>>(x, ca, att, out);
}

// Round 7
// 117.289 us; speedup vs baseline: 1.5251x; 1.5251x over previous
//
#include <hip/hip_runtime.h>
#include <hip/hip_bf16.h>

#define B_ 64
#define C_ 512
#define HW_ 1024
#define R_ 32
#define NCHUNK 4
#define CPB 128   // channels per chunk
#define Q_ 4      // pixel quarters
#define PPB 256   // pixels per block

// ---------------------------------------------------------------------------
// 8-lane group sum on the VALU pipe (DPP), no LDS traffic.
// xor1 = quad_perm[1,0,3,2] (0xB1), xor2 = quad_perm[2,3,0,1] (0x4E),
// then row_half_mirror (0x141) folds the two quads of each 8-lane group.
// ---------------------------------------------------------------------------
__device__ __forceinline__ float dpp_fold8(float s) {
    int y;
    y = __builtin_amdgcn_update_dpp(0, __float_as_int(s), 0xB1, 0xF, 0xF, true);
    s += __int_as_float(y);
    y = __builtin_amdgcn_update_dpp(0, __float_as_int(s), 0x4E, 0xF, 0xF, true);
    s += __int_as_float(y);
    y = __builtin_amdgcn_update_dpp(0, __float_as_int(s), 0x141, 0xF, 0xF, true);
    s += __int_as_float(y);
    return s;
}

// ---------------------------------------------------------------------------
// A0: transpose w_eig (R,C) -> wt (C,R): per-channel rows of 32 contiguous,
// so k_proj's uniform weight reads become s_load_dwordx16 streams.
// ---------------------------------------------------------------------------
__global__ void k_transpose_w(const float* __restrict__ w_eig,
                              float* __restrict__ wt) {
    int idx = blockIdx.x * 1024 + threadIdx.x;   // grid 16 x 1024 = 16384
    int r = idx >> 9;
    int c = idx & 511;
    wt[c * R_ + r] = w_eig[idx];                 // w_eig[r*512 + c]
}

// ---------------------------------------------------------------------------
// A: one pass over x. Block = (b, c-chunk, pixel-quarter); 256 threads,
// 1 pixel/thread; grid 1024. Weights read at THREAD-UNIFORM global
// addresses -> scalar loads into SGPRs (no LDS pipe, no VGPR cost).
// Pooled partial via DPP 8-lane fold + one conditional ds_write.
// ---------------------------------------------------------------------------
__global__ __launch_bounds__(256, 4) void k_proj(
    const float* __restrict__ x, const float* __restrict__ wt,
    const float* __restrict__ w_sp,
    __hip_bfloat16* __restrict__ featp, __hip_bfloat16* __restrict__ sppb,
    float* __restrict__ pooledp)
{
    const int t   = threadIdx.x;         // 0..255
    const int blk = blockIdx.x;          // ((b*4)+ch)*4 + q
    const int q   = blk & 3;
    const int ch  = (blk >> 2) & 3;
    const int b   = blk >> 4;
    const int c0  = ch * CPB;
    const int n   = q * PPB + t;         // this thread's pixel

    __shared__ float plds[CPB][33];      // 16.9 KB pooled partials
    __shared__ float red2[CPB][2];       // 1 KB

    const float* wch = wt + (size_t)c0 * R_;   // uniform base

    float acc[R_];
#pragma unroll
    for (int r = 0; r < R_; ++r) acc[r] = 0.f;
    float sp = 0.f;

    const float* xb = x + ((size_t)(b * C_ + c0)) * HW_ + n;

    float xv = xb[0];
#pragma unroll 2
    for (int j = 0; j < CPB; ++j) {
        // prefetch next channel's pixel (wraps harmlessly on last iter)
        float xn = xb[(size_t)((j + 1) & (CPB - 1)) * HW_];

        // 32 weights at a uniform address -> s_load into SGPRs
        const float4* wr = (const float4*)(wch + j * R_);
#pragma unroll
        for (int k = 0; k < 8; ++k) {
            float4 w = wr[k];
            acc[4 * k + 0] = fmaf(w.x, xv, acc[4 * k + 0]);
            acc[4 * k + 1] = fmaf(w.y, xv, acc[4 * k + 1]);
            acc[4 * k + 2] = fmaf(w.z, xv, acc[4 * k + 2]);
            acc[4 * k + 3] = fmaf(w.w, xv, acc[4 * k + 3]);
        }

        sp = fmaf(w_sp[c0 + j], xv, sp);   // uniform -> s_load

        // pooled partial: DPP 8-lane fold (VALU), one store per 8 lanes
        float s = dpp_fold8(xv);
        if ((t & 7) == 0) plds[j][t >> 3] = s;   // 32 partials per channel

        xv = xn;
    }
    __syncthreads();

    // pooled final reduce: thread t -> channel t>>1, half t&1 (16 values)
    {
        const int j = t >> 1, h = t & 1;
        float s = 0.f;
#pragma unroll
        for (int i = 0; i < 16; ++i) s += plds[j][h * 16 + i];
        red2[j][h] = s;
    }
    __syncthreads();
    if (t < CPB)
        pooledp[(((size_t)q * B_ + b) * C_) + c0 + t] = red2[t][0] + red2[t][1];

    sppb[((size_t)(ch * B_ + b)) * HW_ + n] = __float2bfloat16(sp);

    // featp bf16, layout [(ch*B+b)*HW + n][r] -> 64B per thread
    __hip_bfloat16* fb = featp + ((size_t)((ch * B_ + b) * HW_ + n)) * R_;
    union { __hip_bfloat16 h[R_]; uint4 qv[4]; } u;
#pragma unroll
    for (int r = 0; r < R_; ++r) u.h[r] = __float2bfloat16(acc[r]);
#pragma unroll
    for (int k = 0; k < 4; ++k) ((uint4*)fb)[k] = u.qv[k];
}

// ---------------------------------------------------------------------------
// B: per-batch block (64 blocks, 1024 threads = one per pixel).
// Power-iteration reduction: DPP 8-lane fold -> 128 f32 partials per r,
// packed float2 stores (16 ds_write/wave/iter instead of 192 ds_swizzle),
// then 2-stage combine. Everything else as the passing structure.
// ---------------------------------------------------------------------------
__global__ __launch_bounds__(1024) void k_eigen(
    const __hip_bfloat16* __restrict__ featp,
    const __hip_bfloat16* __restrict__ sppb,
    const float* __restrict__ pooledp,
    const float* __restrict__ w_eig, const float* __restrict__ w_fc1,
    const float* __restrict__ b_fc1, const float* __restrict__ w_fc2,
    const float* __restrict__ b_fc2, const float* __restrict__ b_sp,
    const float* __restrict__ v0,
    float* __restrict__ ca_out, float* __restrict__ att_out)
{
    const int b    = blockIdx.x;
    const int t    = threadIdx.x;
    const int lane = t & 63;
    const int wave = t >> 6;

    __shared__ float pooledm[C_];
    __shared__ float meanv[R_], t1[R_], vv[R_], wred[R_];
    __shared__ float plds2[R_ / 2][128][2];   // 16 KB: [r>>1][partial][r&1]
    __shared__ float redmn[16], redmx[16], scal[2];

    // ---- pooled mean: combine the 4 pixel-quarter partials
    if (t < C_) {
        float s = 0.f;
#pragma unroll
        for (int qq = 0; qq < Q_; ++qq)
            s += pooledp[((size_t)qq * B_ + b) * C_ + t];
        pooledm[t] = s * (1.f / 1024.f);
    }
    __syncthreads();

    // ---- mean[r] = (w_eig @ pooled_mean)[r]; t1[r] = relu(fc1 @ pm + b)
    if (t < 512) {
        const int r = t >> 4, k = t & 15;
        float pm = 0.f, pf = 0.f;
        for (int c = k; c < C_; c += 16) {
            float p = pooledm[c];
            pm = fmaf(w_eig[r * C_ + c], p, pm);
            pf = fmaf(w_fc1[r * C_ + c], p, pf);
        }
#pragma unroll
        for (int m = 8; m > 0; m >>= 1) {
            pm += __shfl_xor(pm, m, 64);
            pf += __shfl_xor(pf, m, 64);
        }
        if (k == 0) { meanv[r] = pm; t1[r] = fmaxf(pf + b_fc1[r], 0.f); }
    }
    __syncthreads();

    // ---- channel attention ca[c] = sigmoid(w_fc2[c,:] @ t1 + b_fc2[c])
    if (t < C_) {
        float s = b_fc2[t];
        const float4* w4 = (const float4*)(w_fc2 + (size_t)t * R_);
#pragma unroll
        for (int k = 0; k < 8; ++k) {
            float4 w = w4[k];
            s = fmaf(w.x, t1[4 * k + 0], s);
            s = fmaf(w.y, t1[4 * k + 1], s);
            s = fmaf(w.z, t1[4 * k + 2], s);
            s = fmaf(w.w, t1[4 * k + 3], s);
        }
        ca_out[b * C_ + t] = 1.f / (1.f + expf(-s));
    }

    // ---- build centered column F_c[:, t] in registers (b_eig cancels)
    float col[R_];
#pragma unroll
    for (int r = 0; r < R_; ++r) col[r] = -meanv[r];
    for (int ch = 0; ch < NCHUNK; ++ch) {
        union { __hip_bfloat16 h[R_]; uint4 qv[4]; } u;
        const uint4* src =
            (const uint4*)(featp + ((size_t)((ch * B_ + b) * HW_ + t)) * R_);
#pragma unroll
        for (int k = 0; k < 4; ++k) u.qv[k] = src[k];
#pragma unroll
        for (int r = 0; r < R_; ++r) col[r] += __bfloat162float(u.h[r]);
    }

    // ---- v = v0 / ||v0||
    if (t < 64) {
        float vl = (t < R_) ? v0[b * R_ + t] : 0.f;
        float sq = vl * vl;
#pragma unroll
        for (int m = 32; m > 0; m >>= 1) sq += __shfl_xor(sq, m, 64);
        if (t < R_) vv[t] = vl / sqrtf(sq);
    }
    __syncthreads();

    // ---- 5 power iterations: v <- normalize(F (F^T v)/1023 + 1e-5 v)
    for (int it = 0; it < 5; ++it) {
        float uacc = 0.f;
#pragma unroll
        for (int r = 0; r < R_; ++r) uacc = fmaf(col[r], vv[r], uacc);
        uacc *= (1.f / 1023.f);

        // stage 1: DPP 8-lane fold, packed float2 store (r pair)
#pragma unroll
        for (int g = 0; g < R_ / 2; ++g) {
            float s0 = dpp_fold8(col[2 * g + 0] * uacc);
            float s1 = dpp_fold8(col[2 * g + 1] * uacc);
            if ((t & 7) == 0) {
                plds2[g][t >> 3][0] = s0;
                plds2[g][t >> 3][1] = s1;
            }
        }
        __syncthreads();

        // stage 2: r = t>>5, i = t&31 sums its 4 partials, 5-level fold
        {
            const int r = t >> 5, i = t & 31;
            const int g = r >> 1, e = r & 1;
            float s = plds2[g][i][e] + plds2[g][i + 32][e] +
                      plds2[g][i + 64][e] + plds2[g][i + 96][e];
#pragma unroll
            for (int m = 16; m > 0; m >>= 1) s += __shfl_xor(s, m, 64);
            if (i == 0) wred[r] = s;
        }
        __syncthreads();

        if (t < 64) {
            float w = (t < R_) ? wred[t] + 1e-5f * vv[t] : 0.f;
            float sq = w * w;
#pragma unroll
            for (int m = 32; m > 0; m >>= 1) sq += __shfl_xor(sq, m, 64);
            if (t < R_) vv[t] = w / (sqrtf(sq) + 1e-10f);
        }
        __syncthreads();
    }

    // ---- att, min/max, eigen_att, spatial_att
    float a = 0.f;
#pragma unroll
    for (int r = 0; r < R_; ++r) a = fmaf(col[r], vv[r], a);

    float mn = a, mx = a;
#pragma unroll
    for (int m = 32; m > 0; m >>= 1) {
        mn = fminf(mn, __shfl_xor(mn, m, 64));
        mx = fmaxf(mx, __shfl_xor(mx, m, 64));
    }
    if (lane == 0) { redmn[wave] = mn; redmx[wave] = mx; }
    __syncthreads();
    if (t == 0) {
        float m1 = redmn[0], m2 = redmx[0];
        for (int w = 1; w < 16; ++w) {
            m1 = fminf(m1, redmn[w]);
            m2 = fmaxf(m2, redmx[w]);
        }
        scal[0] = m1; scal[1] = m2;
    }
    __syncthreads();

    const float amin  = scal[0];
    const float denom = (scal[1] - scal[0]) + 1e-10f;
    float eig = 1.f / (1.f + expf(-((a - amin) / denom)));

    float ssum = b_sp[0];
#pragma unroll
    for (int ch = 0; ch < NCHUNK; ++ch)
        ssum += __bfloat162float(sppb[((size_t)(ch * B_ + b)) * HW_ + t]);
    float spsig = 1.f / (1.f + expf(-ssum));

    att_out[b * HW_ + t] = eig * spsig;
}

// ---------------------------------------------------------------------------
// C: out = x * (1 + ca[b,c] * att_all[b,n]), float4 streaming.
// ---------------------------------------------------------------------------
__global__ __launch_bounds__(256) void k_final(
    const float* __restrict__ x, const float* __restrict__ ca,
    const float* __restrict__ att, float* __restrict__ out)
{
    const int t   = threadIdx.x;
    const int blk = blockIdx.x;          // b*C_ + c
    const int b   = blk >> 9;
    const float cav  = ca[blk];
    const size_t base = (size_t)blk * HW_;

    float4 xv = ((const float4*)(x + base))[t];
    float4 av = ((const float4*)(att + (size_t)b * HW_))[t];
    float4 o;
    o.x = fmaf(xv.x * cav, av.x, xv.x);
    o.y = fmaf(xv.y * cav, av.y, xv.y);
    o.z = fmaf(xv.z * cav, av.z, xv.z);
    o.w = fmaf(xv.w * cav, av.w, xv.w);
    ((float4*)(out + base))[t] = o;
}

// ---------------------------------------------------------------------------
extern "C" void kernel_launch(void* const* d_in, const int* in_sizes, int n_in,
                              void* d_out, int out_size, void* d_ws, size_t ws_size,
                              hipStream_t stream) {
    const float* x     = (const float*)d_in[0];
    const float* w_fc1 = (const float*)d_in[1];
    const float* b_fc1 = (const float*)d_in[2];
    const float* w_fc2 = (const float*)d_in[3];
    const float* b_fc2 = (const float*)d_in[4];
    const float* w_eig = (const float*)d_in[5];
    // d_in[6] = b_eig: cancels under mean-centering; unused.
    const float* w_sp  = (const float*)d_in[7];
    const float* b_sp  = (const float*)d_in[8];
    const float* v0    = (const float*)d_in[9];
    float* out = (float*)d_out;

    // workspace layout (bytes); total 18,284,544 (< proven 18,415,616)
    char* ws = (char*)d_ws;
    __hip_bfloat16* featp = (__hip_bfloat16*)ws;             // 16,777,216: 4*64*1024*32 bf16
    __hip_bfloat16* sppb  = (__hip_bfloat16*)(ws + 16777216);//    524,288: 4*64*1024 bf16
    float* pooledp = (float*)(ws + 17301504);                //    524,288: 4*64*512 f32
    float* ca      = (float*)(ws + 17825792);                //    131,072: 64*512 f32
    float* att     = (float*)(ws + 17956864);                //    262,144: 64*1024 f32
    float* wt      = (float*)(ws + 18219008);                //     65,536: 512*32 f32

    k_transpose_w<<<16, 1024, 0, stream>>>(w_eig, wt);
    k_proj<<<B_ * NCHUNK * Q_, 256, 0, stream>>>(x, wt, w_sp,
                                                 featp, sppb, pooledp);
    k_eigen<<<B_, 1024, 0, stream>>>(featp, sppb, pooledp, w_eig, w_fc1, b_fc1,
                                     w_fc2, b_fc2, b_sp, v0, ca, att);
    k_final<<<B_ * C_, 256, 0, stream>>>(x, ca, att, out);
}